// Round 2
// baseline (1593.008 us; speedup 1.0000x reference)
//
#include <hip/hip_runtime.h>

// LightGCN 3-hop propagation on MI355X.
// Strategy: build dual-direction CSR once per launch (counting sort),
// then 3 gather-based aggregation passes (no float atomics), each fusing
// segment-sum + L2-normalize + residual accumulate.

#define NU     100000
#define NE     100000
#define DD     64
#define NNZ    3200000
#define NROWS  200000            // NE entity rows then NU user rows
#define EMB    6400000           // 100000 * 64

// ---------------------------------------------------------------- init
// copy input embeddings into cur buffers and d_out, zero histogram counts
__global__ void k_init(const float4* __restrict__ uemb,
                       const float4* __restrict__ eemb,
                       float4* __restrict__ ucur, float4* __restrict__ ecur,
                       float4* __restrict__ out, int* __restrict__ counts) {
    const int n4 = EMB / 4;  // 1.6M float4 per table
    int tid = blockIdx.x * blockDim.x + threadIdx.x;
    int stride = gridDim.x * blockDim.x;
    for (int i = tid; i < n4; i += stride) {
        float4 u = uemb[i], e = eemb[i];
        ucur[i] = u;
        ecur[i] = e;
        out[i]      = e;      // entity_res initialized to entity_emb
        out[n4 + i] = u;      // user_res initialized to user_emb
    }
    for (int i = tid; i < NROWS; i += stride) counts[i] = 0;
}

// ---------------------------------------------------------------- histogram
__global__ void k_hist(const int* __restrict__ eu, const int* __restrict__ ee,
                       int* __restrict__ counts) {
    int tid = blockIdx.x * blockDim.x + threadIdx.x;
    int stride = gridDim.x * blockDim.x;
    for (int i = tid; i < NNZ; i += stride) {
        atomicAdd(&counts[ee[i]], 1);        // entity-destination rows
        atomicAdd(&counts[NE + eu[i]], 1);   // user-destination rows
    }
}

// ---------------------------------------------------------------- scan (3 kernels)
__global__ void k_blocksum(const int* __restrict__ counts, int* __restrict__ partials) {
    int gid = blockIdx.x * 256 + threadIdx.x;
    int v = (gid < NROWS) ? counts[gid] : 0;
    for (int d = 32; d; d >>= 1) v += __shfl_down(v, d);
    __shared__ int wsum[4];
    if ((threadIdx.x & 63) == 0) wsum[threadIdx.x >> 6] = v;
    __syncthreads();
    if (threadIdx.x == 0) partials[blockIdx.x] = wsum[0] + wsum[1] + wsum[2] + wsum[3];
}

__global__ void k_scanpartials(int* __restrict__ partials, int nb) {
    // single block, 1024 threads, exclusive scan in place (nb <= 1024)
    int tid = threadIdx.x;
    int v = (tid < nb) ? partials[tid] : 0;
    int lane = tid & 63, wid = tid >> 6;
    int x = v;
    for (int d = 1; d < 64; d <<= 1) { int t = __shfl_up(x, d); if (lane >= d) x += t; }
    __shared__ int wsum[16], woff[16];
    if (lane == 63) wsum[wid] = x;
    __syncthreads();
    if (tid < 16) {
        int s = 0;
        for (int i = 0; i < tid; i++) s += wsum[i];
        woff[tid] = s;
    }
    __syncthreads();
    int excl = x + woff[wid] - v;
    if (tid < nb) partials[tid] = excl;
}

__global__ void k_scanfinal(const int* __restrict__ counts, const int* __restrict__ partials,
                            int* __restrict__ row_ptr, int* __restrict__ cursor) {
    int gid = blockIdx.x * 256 + threadIdx.x;
    int v = (gid < NROWS) ? counts[gid] : 0;
    int lane = threadIdx.x & 63, wid = threadIdx.x >> 6;
    int x = v;
    for (int d = 1; d < 64; d <<= 1) { int t = __shfl_up(x, d); if (lane >= d) x += t; }
    __shared__ int wsum[4];
    if (lane == 63) wsum[wid] = x;
    __syncthreads();
    int add = 0;
    for (int i = 0; i < wid; i++) add += wsum[i];
    int excl = x - v + add + partials[blockIdx.x];
    if (gid < NROWS) { row_ptr[gid] = excl; cursor[gid] = excl; }
    if (gid == NROWS - 1) row_ptr[NROWS] = excl + v;
}

// ---------------------------------------------------------------- fill CSR
// edges[p] = (src_col, bitcast(weight)) packed so one 8B load fetches both.
__global__ void k_fill(const int* __restrict__ eu, const int* __restrict__ ee,
                       const float* __restrict__ ew,
                       int* __restrict__ cursor, int2* __restrict__ edges) {
    int tid = blockIdx.x * blockDim.x + threadIdx.x;
    int stride = gridDim.x * blockDim.x;
    for (int i = tid; i < NNZ; i += stride) {
        int u = eu[i], e = ee[i];
        int wbits = __float_as_int(ew[i]);
        int p = atomicAdd(&cursor[e], 1);       // entity-dest edge: src is user u
        edges[p] = make_int2(u, wbits);
        int q = atomicAdd(&cursor[NE + u], 1);  // user-dest edge: src is entity e
        edges[q] = make_int2(e, wbits);
    }
}

// ---------------------------------------------------------------- aggregation
// One wave per destination row; lane = feature index (D=64).
// Fuses segment-sum, L2-normalize, write of next-hop embedding, residual add.
__global__ void __launch_bounds__(256) k_agg(
        const int* __restrict__ row_ptr, const int2* __restrict__ edges,
        const float* __restrict__ uold, const float* __restrict__ eold,
        float* __restrict__ unew, float* __restrict__ enew,
        float* __restrict__ out) {
    int row = blockIdx.x * 4 + (threadIdx.x >> 6);
    if (row >= NROWS) return;
    int lane = threadIdx.x & 63;

    const float* __restrict__ src;
    float* dst; float* op;
    if (row < NE) {                      // entity destination: gather user rows
        src = uold;
        dst = enew + (size_t)row * DD;
        op  = out  + (size_t)row * DD;
    } else {                             // user destination: gather entity rows
        int r = row - NE;
        src = eold;
        dst = unew + (size_t)r * DD;
        op  = out + EMB + (size_t)r * DD;
    }

    int s = row_ptr[row], e = row_ptr[row + 1];
    float acc = 0.f;
    for (int chunk = s; chunk < e; chunk += 64) {
        int n = e - chunk; if (n > 64) n = 64;
        int2 cw = make_int2(0, 0);
        if (lane < n) cw = edges[chunk + lane];
        int k = 0;
        for (; k + 4 <= n; k += 4) {
            int   c0 = __shfl(cw.x, k),     c1 = __shfl(cw.x, k + 1);
            int   c2 = __shfl(cw.x, k + 2), c3 = __shfl(cw.x, k + 3);
            float w0 = __int_as_float(__shfl(cw.y, k));
            float w1 = __int_as_float(__shfl(cw.y, k + 1));
            float w2 = __int_as_float(__shfl(cw.y, k + 2));
            float w3 = __int_as_float(__shfl(cw.y, k + 3));
            float g0 = src[c0 * DD + lane];
            float g1 = src[c1 * DD + lane];
            float g2 = src[c2 * DD + lane];
            float g3 = src[c3 * DD + lane];
            acc = fmaf(w0, g0, acc);
            acc = fmaf(w1, g1, acc);
            acc = fmaf(w2, g2, acc);
            acc = fmaf(w3, g3, acc);
        }
        for (; k < n; k++) {
            int   c0 = __shfl(cw.x, k);
            float w0 = __int_as_float(__shfl(cw.y, k));
            acc = fmaf(w0, src[c0 * DD + lane], acc);
        }
    }

    // L2 norm across the 64 lanes (one row)
    float sq = acc * acc;
    for (int d = 32; d; d >>= 1) sq += __shfl_xor(sq, d);
    float nv = acc / fmaxf(sqrtf(sq), 1e-12f);

    dst[lane] = nv;       // next-hop embedding
    op[lane] += nv;       // residual accumulate into d_out
}

// ---------------------------------------------------------------- launch
extern "C" void kernel_launch(void* const* d_in, const int* in_sizes, int n_in,
                              void* d_out, int out_size, void* d_ws, size_t ws_size,
                              hipStream_t stream) {
    const float* uemb = (const float*)d_in[0];
    const float* eemb = (const float*)d_in[1];
    const int*   eu   = (const int*)d_in[2];
    const int*   ee   = (const int*)d_in[3];
    const float* ew   = (const float*)d_in[4];
    float* out = (float*)d_out;

    // workspace carve-up (~156 MB total)
    char* ws = (char*)d_ws;
    size_t off = 0;
    float* ucur0 = (float*)(ws + off); off += (size_t)EMB * 4;
    float* ucur1 = (float*)(ws + off); off += (size_t)EMB * 4;
    float* ecur0 = (float*)(ws + off); off += (size_t)EMB * 4;
    float* ecur1 = (float*)(ws + off); off += (size_t)EMB * 4;
    int2*  edges   = (int2*)(ws + off);  off += (size_t)(2 * NNZ) * 8;
    int*   row_ptr = (int*)(ws + off);   off += (size_t)(NROWS + 1) * 4;
    int*   cursor  = (int*)(ws + off);   off += (size_t)NROWS * 4;
    int*   counts  = (int*)(ws + off);   off += (size_t)NROWS * 4;
    int*   partials= (int*)(ws + off);   off += 1024 * 4;

    k_init<<<2048, 256, 0, stream>>>((const float4*)uemb, (const float4*)eemb,
                                     (float4*)ucur0, (float4*)ecur0,
                                     (float4*)out, counts);
    k_hist<<<2048, 256, 0, stream>>>(eu, ee, counts);

    const int NB = (NROWS + 255) / 256;  // 782
    k_blocksum<<<NB, 256, 0, stream>>>(counts, partials);
    k_scanpartials<<<1, 1024, 0, stream>>>(partials, NB);
    k_scanfinal<<<NB, 256, 0, stream>>>(counts, partials, row_ptr, cursor);

    k_fill<<<2048, 256, 0, stream>>>(eu, ee, ew, cursor, edges);

    const int AB = (NROWS + 3) / 4;      // 50000 blocks, 4 waves = 4 rows each
    // hop 1: read buf0, write buf1
    k_agg<<<AB, 256, 0, stream>>>(row_ptr, edges, ucur0, ecur0, ucur1, ecur1, out);
    // hop 2: read buf1, write buf0
    k_agg<<<AB, 256, 0, stream>>>(row_ptr, edges, ucur1, ecur1, ucur0, ecur0, out);
    // hop 3: read buf0, write buf1
    k_agg<<<AB, 256, 0, stream>>>(row_ptr, edges, ucur0, ecur0, ucur1, ecur1, out);
}

// Round 3
// 967.738 us; speedup vs baseline: 1.6461x; 1.6461x over previous
//
#include <hip/hip_runtime.h>

// LightGCN 3-hop propagation on MI355X.
// R3: replace scatter-fill (600us, 395MB partial-line writes) with a
// radix-partition counting sort: per-(block,bucket) runs so every output
// line is written by one block -> full line merging in L2.
// Then 3 gather-based aggregation passes (no float atomics), each fusing
// segment-sum + L2-normalize + residual accumulate.

#define NU     100000
#define NE     100000
#define DD     64
#define NNZ    3200000
#define NROWS  200000            // NE entity rows then NU user rows
#define EMB    6400000           // 100000 * 64
#define TOT    6400000           // 2*NNZ records

#define SHIFT  9                 // rows per bucket = 512
#define RPB    512
#define NBUK   391               // ceil(NROWS / RPB)
#define NBLK   512               // partition tiles
#define TILE   (NNZ / NBLK)      // 6250 edges per tile (exact)

// ---------------------------------------------------------------- init
__global__ void k_init(const float4* __restrict__ uemb,
                       const float4* __restrict__ eemb,
                       float4* __restrict__ ucur, float4* __restrict__ ecur,
                       float4* __restrict__ out) {
    const int n4 = EMB / 4;
    int tid = blockIdx.x * blockDim.x + threadIdx.x;
    int stride = gridDim.x * blockDim.x;
    for (int i = tid; i < n4; i += stride) {
        float4 u = uemb[i], e = eemb[i];
        ucur[i] = u;
        ecur[i] = e;
        out[i]      = e;      // entity_res init = entity_emb
        out[n4 + i] = u;      // user_res init = user_emb
    }
}

// ---------------------------------------------------------------- per-(block,bucket) histogram
__global__ void __launch_bounds__(256) k_bhist(const int* __restrict__ eu,
                                               const int* __restrict__ ee,
                                               int* __restrict__ pos) {
    __shared__ int h[NBUK];
    int t = threadIdx.x;
    for (int b = t; b < NBUK; b += 256) h[b] = 0;
    __syncthreads();
    int start = blockIdx.x * TILE, end = start + TILE;
    for (int i = start + t; i < end; i += 256) {
        atomicAdd(&h[ee[i] >> SHIFT], 1);
        atomicAdd(&h[(NE + eu[i]) >> SHIFT], 1);
    }
    __syncthreads();
    for (int b = t; b < NBUK; b += 256) pos[b * NBLK + blockIdx.x] = h[b];
}

// ---------------------------------------------------------------- generic 3-kernel exclusive scan
__global__ void k_gsum(const int* __restrict__ a, int* __restrict__ partials, int n) {
    int gid = blockIdx.x * 256 + threadIdx.x;
    int v = (gid < n) ? a[gid] : 0;
    for (int d = 32; d; d >>= 1) v += __shfl_down(v, d);
    __shared__ int ws[4];
    if ((threadIdx.x & 63) == 0) ws[threadIdx.x >> 6] = v;
    __syncthreads();
    if (threadIdx.x == 0) partials[blockIdx.x] = ws[0] + ws[1] + ws[2] + ws[3];
}

__global__ void k_gtop(int* __restrict__ partials, int nb) {
    // single block, 1024 threads, exclusive scan in place (nb <= 1024)
    int tid = threadIdx.x;
    int v = (tid < nb) ? partials[tid] : 0;
    int lane = tid & 63, wid = tid >> 6;
    int x = v;
    for (int d = 1; d < 64; d <<= 1) { int tv = __shfl_up(x, d); if (lane >= d) x += tv; }
    __shared__ int wsum[16], woff[16];
    if (lane == 63) wsum[wid] = x;
    __syncthreads();
    if (tid < 16) {
        int s = 0;
        for (int i = 0; i < tid; i++) s += wsum[i];
        woff[tid] = s;
    }
    __syncthreads();
    int excl = x + woff[wid] - v;
    if (tid < nb) partials[tid] = excl;
}

__global__ void k_gfinal(int* __restrict__ a, const int* __restrict__ partials, int n) {
    int gid = blockIdx.x * 256 + threadIdx.x;
    int v = (gid < n) ? a[gid] : 0;
    int lane = threadIdx.x & 63, wid = threadIdx.x >> 6;
    int x = v;
    for (int d = 1; d < 64; d <<= 1) { int tv = __shfl_up(x, d); if (lane >= d) x += tv; }
    __shared__ int ws[4];
    if (lane == 63) ws[wid] = x;
    __syncthreads();
    int add = 0;
    for (int i = 0; i < wid; i++) add += ws[i];
    int excl = x - v + add + partials[blockIdx.x];
    if (gid < n) a[gid] = excl;
}

// ---------------------------------------------------------------- partition pass B
// Append records into bucket-major staging; each (block,bucket) run is a
// private contiguous range -> coalesced full-line writes from one block.
// rec.x = (row_in_bucket << 17) | src_col   (col < 2^17, rib < 512)
__global__ void __launch_bounds__(256) k_partB(const int* __restrict__ eu,
                                               const int* __restrict__ ee,
                                               const float* __restrict__ ew,
                                               const int* __restrict__ pos,
                                               int2* __restrict__ recs) {
    __shared__ int cur[NBUK];
    int t = threadIdx.x;
    for (int b = t; b < NBUK; b += 256) cur[b] = pos[b * NBLK + blockIdx.x];
    __syncthreads();
    int start = blockIdx.x * TILE, end = start + TILE;
    for (int i = start + t; i < end; i += 256) {
        int u = eu[i], e = ee[i];
        int wb = __float_as_int(ew[i]);
        int r1 = e;                         // entity-dest row, src = user u
        int p1 = atomicAdd(&cur[r1 >> SHIFT], 1);
        recs[p1] = make_int2(((r1 & (RPB - 1)) << 17) | u, wb);
        int r2 = NE + u;                    // user-dest row, src = entity e
        int p2 = atomicAdd(&cur[r2 >> SHIFT], 1);
        recs[p2] = make_int2(((r2 & (RPB - 1)) << 17) | e, wb);
    }
}

// ---------------------------------------------------------------- partition pass C
// One block per bucket: per-row LDS histogram + scan -> row_ptr, then
// scatter records to final CSR order (writes stay in ~130KB L2-hot window).
__global__ void __launch_bounds__(256) k_partC(const int* __restrict__ pos,
                                               const int2* __restrict__ recs,
                                               int2* __restrict__ edges,
                                               int* __restrict__ row_ptr) {
    int b = blockIdx.x;
    int t = threadIdx.x;
    __shared__ int hist[RPB];
    __shared__ int curs[RPB];
    __shared__ int wtot[4];
    int base = pos[b * NBLK];
    int nend = (b == NBUK - 1) ? TOT : pos[(b + 1) * NBLK];
    for (int r = t; r < RPB; r += 256) hist[r] = 0;
    __syncthreads();
    for (int i = base + t; i < nend; i += 256)
        atomicAdd(&hist[recs[i].x >> 17], 1);
    __syncthreads();
    // exclusive scan of RPB=512 entries with 256 threads (2 each)
    int h0 = hist[2 * t], h1 = hist[2 * t + 1];
    int s = h0 + h1;
    int lane = t & 63, wid = t >> 6;
    int x = s;
    for (int d = 1; d < 64; d <<= 1) { int v = __shfl_up(x, d); if (lane >= d) x += v; }
    if (lane == 63) wtot[wid] = x;
    __syncthreads();
    int woff = 0;
    for (int i = 0; i < wid; i++) woff += wtot[i];
    int e0 = base + woff + x - s;          // absolute exclusive pos of row 2t
    curs[2 * t]     = e0;
    curs[2 * t + 1] = e0 + h0;
    int row0 = (b << SHIFT) + 2 * t;
    if (row0 < NROWS)     row_ptr[row0]     = e0;
    if (row0 + 1 < NROWS) row_ptr[row0 + 1] = e0 + h0;
    if (b == 0 && t == 0) row_ptr[NROWS]    = TOT;
    __syncthreads();
    for (int i = base + t; i < nend; i += 256) {
        int2 rc = recs[i];
        int p = atomicAdd(&curs[rc.x >> 17], 1);
        edges[p] = make_int2(rc.x & 0x1FFFF, rc.y);
    }
}

// ---------------------------------------------------------------- aggregation (unchanged)
// One wave per destination row; lane = feature index (D=64).
__global__ void __launch_bounds__(256) k_agg(
        const int* __restrict__ row_ptr, const int2* __restrict__ edges,
        const float* __restrict__ uold, const float* __restrict__ eold,
        float* __restrict__ unew, float* __restrict__ enew,
        float* __restrict__ out) {
    int row = blockIdx.x * 4 + (threadIdx.x >> 6);
    if (row >= NROWS) return;
    int lane = threadIdx.x & 63;

    const float* __restrict__ src;
    float* dst; float* op;
    if (row < NE) {                      // entity destination: gather user rows
        src = uold;
        dst = enew + (size_t)row * DD;
        op  = out  + (size_t)row * DD;
    } else {                             // user destination: gather entity rows
        int r = row - NE;
        src = eold;
        dst = unew + (size_t)r * DD;
        op  = out + EMB + (size_t)r * DD;
    }

    int s = row_ptr[row], e = row_ptr[row + 1];
    float acc = 0.f;
    for (int chunk = s; chunk < e; chunk += 64) {
        int n = e - chunk; if (n > 64) n = 64;
        int2 cw = make_int2(0, 0);
        if (lane < n) cw = edges[chunk + lane];
        int k = 0;
        for (; k + 4 <= n; k += 4) {
            int   c0 = __shfl(cw.x, k),     c1 = __shfl(cw.x, k + 1);
            int   c2 = __shfl(cw.x, k + 2), c3 = __shfl(cw.x, k + 3);
            float w0 = __int_as_float(__shfl(cw.y, k));
            float w1 = __int_as_float(__shfl(cw.y, k + 1));
            float w2 = __int_as_float(__shfl(cw.y, k + 2));
            float w3 = __int_as_float(__shfl(cw.y, k + 3));
            float g0 = src[c0 * DD + lane];
            float g1 = src[c1 * DD + lane];
            float g2 = src[c2 * DD + lane];
            float g3 = src[c3 * DD + lane];
            acc = fmaf(w0, g0, acc);
            acc = fmaf(w1, g1, acc);
            acc = fmaf(w2, g2, acc);
            acc = fmaf(w3, g3, acc);
        }
        for (; k < n; k++) {
            int   c0 = __shfl(cw.x, k);
            float w0 = __int_as_float(__shfl(cw.y, k));
            acc = fmaf(w0, src[c0 * DD + lane], acc);
        }
    }

    float sq = acc * acc;
    for (int d = 32; d; d >>= 1) sq += __shfl_xor(sq, d);
    float nv = acc / fmaxf(sqrtf(sq), 1e-12f);

    dst[lane] = nv;       // next-hop embedding
    op[lane] += nv;       // residual accumulate into d_out
}

// ---------------------------------------------------------------- launch
extern "C" void kernel_launch(void* const* d_in, const int* in_sizes, int n_in,
                              void* d_out, int out_size, void* d_ws, size_t ws_size,
                              hipStream_t stream) {
    const float* uemb = (const float*)d_in[0];
    const float* eemb = (const float*)d_in[1];
    const int*   eu   = (const int*)d_in[2];
    const int*   ee   = (const int*)d_in[3];
    const float* ew   = (const float*)d_in[4];
    float* out = (float*)d_out;

    // workspace carve-up (~155 MB); recs aliases ucur1+ecur1 (dead until hop1)
    char* ws = (char*)d_ws;
    size_t off = 0;
    float* ucur0 = (float*)(ws + off); off += (size_t)EMB * 4;
    float* ecur0 = (float*)(ws + off); off += (size_t)EMB * 4;
    float* ucur1 = (float*)(ws + off); off += (size_t)EMB * 4;
    float* ecur1 = (float*)(ws + off); off += (size_t)EMB * 4;
    int2*  recs  = (int2*)ucur1;      // 6.4M * 8B = 51.2MB = ucur1 + ecur1 exactly
    int2*  edges   = (int2*)(ws + off);  off += (size_t)TOT * 8;
    int*   row_ptr = (int*)(ws + off);   off += (size_t)(NROWS + 1) * 4;
    int*   pos     = (int*)(ws + off);   off += (size_t)NBUK * NBLK * 4;
    int*   partials= (int*)(ws + off);   off += 1024 * 4;

    // 1. copy embeddings, init output residuals
    k_init<<<2048, 256, 0, stream>>>((const float4*)uemb, (const float4*)eemb,
                                     (float4*)ucur0, (float4*)ecur0, (float4*)out);

    // 2. per-(block,bucket) histogram
    k_bhist<<<NBLK, 256, 0, stream>>>(eu, ee, pos);

    // 3. exclusive scan of NBUK*NBLK counters (bucket-major)
    const int NSCAN = NBUK * NBLK;               // 200192
    const int NB = (NSCAN + 255) / 256;          // 782
    k_gsum<<<NB, 256, 0, stream>>>(pos, partials, NSCAN);
    k_gtop<<<1, 1024, 0, stream>>>(partials, NB);
    k_gfinal<<<NB, 256, 0, stream>>>(pos, partials, NSCAN);

    // 4. partition into bucket-major staging (coalesced block-owned runs)
    k_partB<<<NBLK, 256, 0, stream>>>(eu, ee, ew, pos, recs);

    // 5. per-bucket scatter to final CSR order + emit row_ptr
    k_partC<<<NBUK, 256, 0, stream>>>(pos, recs, edges, row_ptr);

    // 6. three fused aggregation hops
    const int AB = (NROWS + 3) / 4;      // 50000 blocks, 4 waves = 4 rows each
    k_agg<<<AB, 256, 0, stream>>>(row_ptr, edges, ucur0, ecur0, ucur1, ecur1, out);
    k_agg<<<AB, 256, 0, stream>>>(row_ptr, edges, ucur1, ecur1, ucur0, ecur0, out);
    k_agg<<<AB, 256, 0, stream>>>(row_ptr, edges, ucur0, ecur0, ucur1, ecur1, out);
}

// Round 4
// 800.576 us; speedup vs baseline: 1.9898x; 1.2088x over previous
//
#include <hip/hip_runtime.h>

// LightGCN 3-hop propagation on MI355X.
// R4: gathered tables stored in bf16 (halves the dominant random-gather
// traffic; f32 accumulate/norm/residual). Partition phase unchanged from R3:
// radix-partition counting sort with block-owned coalesced write runs.

#define NU     100000
#define NE     100000
#define DD     64
#define NNZ    3200000
#define NROWS  200000            // NE entity rows then NU user rows
#define EMB    6400000           // 100000 * 64
#define TOT    6400000           // 2*NNZ records

#define SHIFT  9                 // rows per bucket = 512
#define RPB    512
#define NBUK   391               // ceil(NROWS / RPB)
#define NBLK   512               // partition tiles
#define TILE   (NNZ / NBLK)      // 6250 edges per tile (exact)

__device__ __forceinline__ float bf2f(ushort v) {
    return __uint_as_float(((unsigned int)v) << 16);
}
__device__ __forceinline__ ushort f2bf(float x) {
    unsigned int b = __float_as_uint(x);
    return (ushort)((b + 0x7FFF + ((b >> 16) & 1)) >> 16);   // RNE
}

// ---------------------------------------------------------------- init
// f32 inputs -> bf16 gather tables + f32 residual init in d_out
__global__ void k_init(const float4* __restrict__ uemb,
                       const float4* __restrict__ eemb,
                       ushort4* __restrict__ ucur, ushort4* __restrict__ ecur,
                       float4* __restrict__ out) {
    const int n4 = EMB / 4;
    int tid = blockIdx.x * blockDim.x + threadIdx.x;
    int stride = gridDim.x * blockDim.x;
    for (int i = tid; i < n4; i += stride) {
        float4 u = uemb[i], e = eemb[i];
        ushort4 ub, eb;
        ub.x = f2bf(u.x); ub.y = f2bf(u.y); ub.z = f2bf(u.z); ub.w = f2bf(u.w);
        eb.x = f2bf(e.x); eb.y = f2bf(e.y); eb.z = f2bf(e.z); eb.w = f2bf(e.w);
        ucur[i] = ub;
        ecur[i] = eb;
        out[i]      = e;      // entity_res init = entity_emb
        out[n4 + i] = u;      // user_res init = user_emb
    }
}

// ---------------------------------------------------------------- per-(block,bucket) histogram
__global__ void __launch_bounds__(256) k_bhist(const int* __restrict__ eu,
                                               const int* __restrict__ ee,
                                               int* __restrict__ pos) {
    __shared__ int h[NBUK];
    int t = threadIdx.x;
    for (int b = t; b < NBUK; b += 256) h[b] = 0;
    __syncthreads();
    int start = blockIdx.x * TILE, end = start + TILE;
    for (int i = start + t; i < end; i += 256) {
        atomicAdd(&h[ee[i] >> SHIFT], 1);
        atomicAdd(&h[(NE + eu[i]) >> SHIFT], 1);
    }
    __syncthreads();
    for (int b = t; b < NBUK; b += 256) pos[b * NBLK + blockIdx.x] = h[b];
}

// ---------------------------------------------------------------- generic 3-kernel exclusive scan
__global__ void k_gsum(const int* __restrict__ a, int* __restrict__ partials, int n) {
    int gid = blockIdx.x * 256 + threadIdx.x;
    int v = (gid < n) ? a[gid] : 0;
    for (int d = 32; d; d >>= 1) v += __shfl_down(v, d);
    __shared__ int ws[4];
    if ((threadIdx.x & 63) == 0) ws[threadIdx.x >> 6] = v;
    __syncthreads();
    if (threadIdx.x == 0) partials[blockIdx.x] = ws[0] + ws[1] + ws[2] + ws[3];
}

__global__ void k_gtop(int* __restrict__ partials, int nb) {
    int tid = threadIdx.x;
    int v = (tid < nb) ? partials[tid] : 0;
    int lane = tid & 63, wid = tid >> 6;
    int x = v;
    for (int d = 1; d < 64; d <<= 1) { int tv = __shfl_up(x, d); if (lane >= d) x += tv; }
    __shared__ int wsum[16], woff[16];
    if (lane == 63) wsum[wid] = x;
    __syncthreads();
    if (tid < 16) {
        int s = 0;
        for (int i = 0; i < tid; i++) s += wsum[i];
        woff[tid] = s;
    }
    __syncthreads();
    int excl = x + woff[wid] - v;
    if (tid < nb) partials[tid] = excl;
}

__global__ void k_gfinal(int* __restrict__ a, const int* __restrict__ partials, int n) {
    int gid = blockIdx.x * 256 + threadIdx.x;
    int v = (gid < n) ? a[gid] : 0;
    int lane = threadIdx.x & 63, wid = threadIdx.x >> 6;
    int x = v;
    for (int d = 1; d < 64; d <<= 1) { int tv = __shfl_up(x, d); if (lane >= d) x += tv; }
    __shared__ int ws[4];
    if (lane == 63) ws[wid] = x;
    __syncthreads();
    int add = 0;
    for (int i = 0; i < wid; i++) add += ws[i];
    int excl = x - v + add + partials[blockIdx.x];
    if (gid < n) a[gid] = excl;
}

// ---------------------------------------------------------------- partition pass B
// rec.x = (row_in_bucket << 17) | src_col   (col < 2^17, rib < 512)
__global__ void __launch_bounds__(256) k_partB(const int* __restrict__ eu,
                                               const int* __restrict__ ee,
                                               const float* __restrict__ ew,
                                               const int* __restrict__ pos,
                                               int2* __restrict__ recs) {
    __shared__ int cur[NBUK];
    int t = threadIdx.x;
    for (int b = t; b < NBUK; b += 256) cur[b] = pos[b * NBLK + blockIdx.x];
    __syncthreads();
    int start = blockIdx.x * TILE, end = start + TILE;
    for (int i = start + t; i < end; i += 256) {
        int u = eu[i], e = ee[i];
        int wb = __float_as_int(ew[i]);
        int r1 = e;                         // entity-dest row, src = user u
        int p1 = atomicAdd(&cur[r1 >> SHIFT], 1);
        recs[p1] = make_int2(((r1 & (RPB - 1)) << 17) | u, wb);
        int r2 = NE + u;                    // user-dest row, src = entity e
        int p2 = atomicAdd(&cur[r2 >> SHIFT], 1);
        recs[p2] = make_int2(((r2 & (RPB - 1)) << 17) | e, wb);
    }
}

// ---------------------------------------------------------------- partition pass C
__global__ void __launch_bounds__(256) k_partC(const int* __restrict__ pos,
                                               const int2* __restrict__ recs,
                                               int2* __restrict__ edges,
                                               int* __restrict__ row_ptr) {
    int b = blockIdx.x;
    int t = threadIdx.x;
    __shared__ int hist[RPB];
    __shared__ int curs[RPB];
    __shared__ int wtot[4];
    int base = pos[b * NBLK];
    int nend = (b == NBUK - 1) ? TOT : pos[(b + 1) * NBLK];
    for (int r = t; r < RPB; r += 256) hist[r] = 0;
    __syncthreads();
    for (int i = base + t; i < nend; i += 256)
        atomicAdd(&hist[recs[i].x >> 17], 1);
    __syncthreads();
    int h0 = hist[2 * t], h1 = hist[2 * t + 1];
    int s = h0 + h1;
    int lane = t & 63, wid = t >> 6;
    int x = s;
    for (int d = 1; d < 64; d <<= 1) { int v = __shfl_up(x, d); if (lane >= d) x += v; }
    if (lane == 63) wtot[wid] = x;
    __syncthreads();
    int woff = 0;
    for (int i = 0; i < wid; i++) woff += wtot[i];
    int e0 = base + woff + x - s;          // absolute exclusive pos of row 2t
    curs[2 * t]     = e0;
    curs[2 * t + 1] = e0 + h0;
    int row0 = (b << SHIFT) + 2 * t;
    if (row0 < NROWS)     row_ptr[row0]     = e0;
    if (row0 + 1 < NROWS) row_ptr[row0 + 1] = e0 + h0;
    if (b == 0 && t == 0) row_ptr[NROWS]    = TOT;
    __syncthreads();
    for (int i = base + t; i < nend; i += 256) {
        int2 rc = recs[i];
        int p = atomicAdd(&curs[rc.x >> 17], 1);
        edges[p] = make_int2(rc.x & 0x1FFFF, rc.y);
    }
}

// ---------------------------------------------------------------- aggregation
// One wave per destination row; lane = feature index (D=64).
// bf16 gathers, f32 accumulate + norm; writes bf16 next-hop row + f32 residual.
__global__ void __launch_bounds__(256) k_agg(
        const int* __restrict__ row_ptr, const int2* __restrict__ edges,
        const ushort* __restrict__ uold, const ushort* __restrict__ eold,
        ushort* __restrict__ unew, ushort* __restrict__ enew,
        float* __restrict__ out) {
    int row = blockIdx.x * 4 + (threadIdx.x >> 6);
    if (row >= NROWS) return;
    int lane = threadIdx.x & 63;

    const ushort* __restrict__ src;
    ushort* dst; float* op;
    if (row < NE) {                      // entity destination: gather user rows
        src = uold;
        dst = enew + (size_t)row * DD;
        op  = out  + (size_t)row * DD;
    } else {                             // user destination: gather entity rows
        int r = row - NE;
        src = eold;
        dst = unew + (size_t)r * DD;
        op  = out + EMB + (size_t)r * DD;
    }

    int s = row_ptr[row], e = row_ptr[row + 1];
    float acc = 0.f;
    for (int chunk = s; chunk < e; chunk += 64) {
        int n = e - chunk; if (n > 64) n = 64;
        int2 cw = make_int2(0, 0);
        if (lane < n) cw = edges[chunk + lane];
        int k = 0;
        for (; k + 4 <= n; k += 4) {
            int   c0 = __shfl(cw.x, k),     c1 = __shfl(cw.x, k + 1);
            int   c2 = __shfl(cw.x, k + 2), c3 = __shfl(cw.x, k + 3);
            float w0 = __int_as_float(__shfl(cw.y, k));
            float w1 = __int_as_float(__shfl(cw.y, k + 1));
            float w2 = __int_as_float(__shfl(cw.y, k + 2));
            float w3 = __int_as_float(__shfl(cw.y, k + 3));
            float g0 = bf2f(src[c0 * DD + lane]);
            float g1 = bf2f(src[c1 * DD + lane]);
            float g2 = bf2f(src[c2 * DD + lane]);
            float g3 = bf2f(src[c3 * DD + lane]);
            acc = fmaf(w0, g0, acc);
            acc = fmaf(w1, g1, acc);
            acc = fmaf(w2, g2, acc);
            acc = fmaf(w3, g3, acc);
        }
        for (; k < n; k++) {
            int   c0 = __shfl(cw.x, k);
            float w0 = __int_as_float(__shfl(cw.y, k));
            acc = fmaf(w0, bf2f(src[c0 * DD + lane]), acc);
        }
    }

    float sq = acc * acc;
    for (int d = 32; d; d >>= 1) sq += __shfl_xor(sq, d);
    float nv = acc / fmaxf(sqrtf(sq), 1e-12f);

    dst[lane] = f2bf(nv);   // next-hop embedding (bf16)
    op[lane] += nv;         // residual accumulate into d_out (f32)
}

// ---------------------------------------------------------------- launch
extern "C" void kernel_launch(void* const* d_in, const int* in_sizes, int n_in,
                              void* d_out, int out_size, void* d_ws, size_t ws_size,
                              hipStream_t stream) {
    const float* uemb = (const float*)d_in[0];
    const float* eemb = (const float*)d_in[1];
    const int*   eu   = (const int*)d_in[2];
    const int*   ee   = (const int*)d_in[3];
    const float* ew   = (const float*)d_in[4];
    float* out = (float*)d_out;

    // workspace carve-up (~156 MB)
    char* ws = (char*)d_ws;
    size_t off = 0;
    ushort* ucur0 = (ushort*)(ws + off); off += (size_t)EMB * 2;   // 12.8 MB each
    ushort* ecur0 = (ushort*)(ws + off); off += (size_t)EMB * 2;
    ushort* ucur1 = (ushort*)(ws + off); off += (size_t)EMB * 2;
    ushort* ecur1 = (ushort*)(ws + off); off += (size_t)EMB * 2;
    int2*  recs    = (int2*)(ws + off);  off += (size_t)TOT * 8;   // 51.2 MB
    int2*  edges   = (int2*)(ws + off);  off += (size_t)TOT * 8;   // 51.2 MB
    int*   row_ptr = (int*)(ws + off);   off += (size_t)(NROWS + 1) * 4;
    int*   pos     = (int*)(ws + off);   off += (size_t)NBUK * NBLK * 4;
    int*   partials= (int*)(ws + off);   off += 1024 * 4;

    // 1. convert embeddings to bf16 tables, init output residuals
    k_init<<<2048, 256, 0, stream>>>((const float4*)uemb, (const float4*)eemb,
                                     (ushort4*)ucur0, (ushort4*)ecur0, (float4*)out);

    // 2. per-(block,bucket) histogram
    k_bhist<<<NBLK, 256, 0, stream>>>(eu, ee, pos);

    // 3. exclusive scan of NBUK*NBLK counters (bucket-major)
    const int NSCAN = NBUK * NBLK;               // 200192
    const int NB = (NSCAN + 255) / 256;          // 782
    k_gsum<<<NB, 256, 0, stream>>>(pos, partials, NSCAN);
    k_gtop<<<1, 1024, 0, stream>>>(partials, NB);
    k_gfinal<<<NB, 256, 0, stream>>>(pos, partials, NSCAN);

    // 4. partition into bucket-major staging (coalesced block-owned runs)
    k_partB<<<NBLK, 256, 0, stream>>>(eu, ee, ew, pos, recs);

    // 5. per-bucket scatter to final CSR order + emit row_ptr
    k_partC<<<NBUK, 256, 0, stream>>>(pos, recs, edges, row_ptr);

    // 6. three fused aggregation hops
    const int AB = (NROWS + 3) / 4;      // 50000 blocks, 4 waves = 4 rows each
    k_agg<<<AB, 256, 0, stream>>>(row_ptr, edges, ucur0, ecur0, ucur1, ecur1, out);
    k_agg<<<AB, 256, 0, stream>>>(row_ptr, edges, ucur1, ecur1, ucur0, ecur0, out);
    k_agg<<<AB, 256, 0, stream>>>(row_ptr, edges, ucur0, ecur0, ucur1, ecur1, out);
}